// Round 1
// baseline (3399.600 us; speedup 1.0000x reference)
//
#include <hip/hip_runtime.h>

#define NG 16384   // B*L graphs
#define NN 64      // nodes
#define FP 8       // feats per node
#define HD 128     // hidden
#define NM 8       // spectral modes

__global__ __launch_bounds__(256, 2)
void sgn_fused(const float* __restrict__ x,
               const float* __restrict__ adj,
               const float* __restrict__ U,
               const float* __restrict__ Wp, const float* __restrict__ bp,
               const float* __restrict__ w0, const float* __restrict__ w2,
               const float* __restrict__ Ws1, const float* __restrict__ bs1,
               const float* __restrict__ Wn1, const float* __restrict__ bn1,
               const float* __restrict__ g1, const float* __restrict__ be1,
               const float* __restrict__ Ws3, const float* __restrict__ bs3,
               const float* __restrict__ Wn3, const float* __restrict__ bn3,
               const float* __restrict__ g3, const float* __restrict__ be3,
               const float* __restrict__ Wo, const float* __restrict__ bo,
               float* __restrict__ out)
{
    __shared__ float hbuf[NN][HD];   // current activations (64x128)
    __shared__ float tbuf[NN][HD];   // hn_in scratch
    __shared__ float Ubuf[NN][NM];   // U[:, :8]
    __shared__ float xfT[HD][NM];    // xf transposed: [channel][mode]
    __shared__ float ofbuf[NM][HD];  // of: [mode][channel]
    __shared__ float Sbuf[HD];       // column sums

    const int b    = blockIdx.x;
    const int t    = threadIdx.x;
    const int wave = t >> 6;
    const int lane = t & 63;
    const int row0 = wave * 16;      // this wave owns rows [row0, row0+16)
    const int cA   = lane;           // this lane owns cols cA and cB
    const int cB   = lane + 64;

    const float sadj = adj[1];       // off-diagonal value = 1/(63+1e-8)

    // preload U[:, :8]
    for (int idx = t; idx < NN * NM; idx += 256) {
        const int n = idx >> 3, k = idx & 7;
        Ubuf[n][k] = U[n * NN + k];
    }

    // ---------------- input projection: h = x @ Wp + bp ----------------
    {
        float wpA[FP], wpB[FP];
        #pragma unroll
        for (int f = 0; f < FP; ++f) { wpA[f] = Wp[f*HD + cA]; wpB[f] = Wp[f*HD + cB]; }
        const float bpA = bp[cA], bpB = bp[cB];
        const float* xb = x + (size_t)b * (NN*FP);
        #pragma unroll
        for (int r = 0; r < 16; ++r) {
            const int n = row0 + r;
            const float4 x0 = *reinterpret_cast<const float4*>(xb + n*FP);
            const float4 x1 = *reinterpret_cast<const float4*>(xb + n*FP + 4);
            float aA = bpA, aB = bpB;
            aA = fmaf(x0.x, wpA[0], aA); aA = fmaf(x0.y, wpA[1], aA);
            aA = fmaf(x0.z, wpA[2], aA); aA = fmaf(x0.w, wpA[3], aA);
            aA = fmaf(x1.x, wpA[4], aA); aA = fmaf(x1.y, wpA[5], aA);
            aA = fmaf(x1.z, wpA[6], aA); aA = fmaf(x1.w, wpA[7], aA);
            aB = fmaf(x0.x, wpB[0], aB); aB = fmaf(x0.y, wpB[1], aB);
            aB = fmaf(x0.z, wpB[2], aB); aB = fmaf(x0.w, wpB[3], aB);
            aB = fmaf(x1.x, wpB[4], aB); aB = fmaf(x1.y, wpB[5], aB);
            aB = fmaf(x1.z, wpB[6], aB); aB = fmaf(x1.w, wpB[7], aB);
            hbuf[n][cA] = aA;
            hbuf[n][cB] = aB;
        }
    }
    __syncthreads();

    // ---------------- spectral layer ----------------
    auto spectral = [&](const float* __restrict__ w) {
        // xf[k][c] = sum_m U[m][k] * h[m][c]   (keep first 8 modes)
        {
            const int c  = t & 127;
            const int k0 = (t >> 7) * 4;   // waves 0,1 -> k 0..3 ; waves 2,3 -> k 4..7
            float a0=0.f, a1=0.f, a2=0.f, a3=0.f;
            for (int m = 0; m < NN; ++m) {
                const float hv = hbuf[m][c];
                const float4 uv = *reinterpret_cast<const float4*>(&Ubuf[m][k0]);
                a0 = fmaf(uv.x, hv, a0); a1 = fmaf(uv.y, hv, a1);
                a2 = fmaf(uv.z, hv, a2); a3 = fmaf(uv.w, hv, a3);
            }
            xfT[c][k0+0] = a0; xfT[c][k0+1] = a1;
            xfT[c][k0+2] = a2; xfT[c][k0+3] = a3;
        }
        __syncthreads();
        // of[k][j] = sum_i xf[k][i] * w[i][j][k]
        {
            const int j  = t & 127;
            const int k0 = (t >> 7) * 4;
            float a0=0.f, a1=0.f, a2=0.f, a3=0.f;
            for (int i = 0; i < HD; ++i) {
                const float4 xv = *reinterpret_cast<const float4*>(&xfT[i][k0]);
                const float4 wv = *reinterpret_cast<const float4*>(&w[((i*HD) + j)*NM + k0]);
                a0 = fmaf(xv.x, wv.x, a0); a1 = fmaf(xv.y, wv.y, a1);
                a2 = fmaf(xv.z, wv.z, a2); a3 = fmaf(xv.w, wv.w, a3);
            }
            ofbuf[k0+0][j] = a0; ofbuf[k0+1][j] = a1;
            ofbuf[k0+2][j] = a2; ofbuf[k0+3][j] = a3;
        }
        __syncthreads();
        // h_new[n][c] = sum_k U[n][k] * of[k][c]
        {
            float ofA[NM], ofB[NM];
            #pragma unroll
            for (int k = 0; k < NM; ++k) { ofA[k] = ofbuf[k][cA]; ofB[k] = ofbuf[k][cB]; }
            #pragma unroll
            for (int r = 0; r < 16; ++r) {
                const int n = row0 + r;
                const float4 u0 = *reinterpret_cast<const float4*>(&Ubuf[n][0]);
                const float4 u1 = *reinterpret_cast<const float4*>(&Ubuf[n][4]);
                float aA = 0.f, aB = 0.f;
                aA = fmaf(u0.x, ofA[0], aA); aA = fmaf(u0.y, ofA[1], aA);
                aA = fmaf(u0.z, ofA[2], aA); aA = fmaf(u0.w, ofA[3], aA);
                aA = fmaf(u1.x, ofA[4], aA); aA = fmaf(u1.y, ofA[5], aA);
                aA = fmaf(u1.z, ofA[6], aA); aA = fmaf(u1.w, ofA[7], aA);
                aB = fmaf(u0.x, ofB[0], aB); aB = fmaf(u0.y, ofB[1], aB);
                aB = fmaf(u0.z, ofB[2], aB); aB = fmaf(u0.w, ofB[3], aB);
                aB = fmaf(u1.x, ofB[4], aB); aB = fmaf(u1.y, ofB[5], aB);
                aB = fmaf(u1.z, ofB[6], aB); aB = fmaf(u1.w, ofB[7], aB);
                hbuf[n][cA] = aA;
                hbuf[n][cB] = aB;
            }
        }
        __syncthreads();
    };

    // ---------------- graph conv layer ----------------
    auto conv = [&](const float* __restrict__ Ws, const float* __restrict__ bs,
                    const float* __restrict__ Wn, const float* __restrict__ bn,
                    const float* __restrict__ g,  const float* __restrict__ be) {
        // column sums (for adj trick)
        if (t < HD) {
            float s = 0.f;
            for (int n = 0; n < NN; ++n) s += hbuf[n][t];
            Sbuf[t] = s;
        }
        __syncthreads();
        // hn_in[n][c] = s * (S[c] - h[n][c])
        const float SA = Sbuf[cA], SB = Sbuf[cB];
        #pragma unroll
        for (int r = 0; r < 16; ++r) {
            const int n = row0 + r;
            tbuf[n][cA] = sadj * (SA - hbuf[n][cA]);
            tbuf[n][cB] = sadj * (SB - hbuf[n][cB]);
        }
        // o = h @ Ws + hn_in @ Wn + (bs + bn)
        float accA[16], accB[16];
        const float b0A = bs[cA] + bn[cA];
        const float b0B = bs[cB] + bn[cB];
        #pragma unroll
        for (int r = 0; r < 16; ++r) { accA[r] = b0A; accB[r] = b0B; }

        for (int i0 = 0; i0 < HD; i0 += 4) {
            float wA[4], wB[4];
            #pragma unroll
            for (int q = 0; q < 4; ++q) { wA[q] = Ws[(i0+q)*HD + cA]; wB[q] = Ws[(i0+q)*HD + cB]; }
            #pragma unroll
            for (int r = 0; r < 16; ++r) {
                const float4 hv = *reinterpret_cast<const float4*>(&hbuf[row0+r][i0]);
                accA[r] = fmaf(hv.x, wA[0], accA[r]); accA[r] = fmaf(hv.y, wA[1], accA[r]);
                accA[r] = fmaf(hv.z, wA[2], accA[r]); accA[r] = fmaf(hv.w, wA[3], accA[r]);
                accB[r] = fmaf(hv.x, wB[0], accB[r]); accB[r] = fmaf(hv.y, wB[1], accB[r]);
                accB[r] = fmaf(hv.z, wB[2], accB[r]); accB[r] = fmaf(hv.w, wB[3], accB[r]);
            }
        }
        for (int i0 = 0; i0 < HD; i0 += 4) {
            float wA[4], wB[4];
            #pragma unroll
            for (int q = 0; q < 4; ++q) { wA[q] = Wn[(i0+q)*HD + cA]; wB[q] = Wn[(i0+q)*HD + cB]; }
            #pragma unroll
            for (int r = 0; r < 16; ++r) {
                const float4 hv = *reinterpret_cast<const float4*>(&tbuf[row0+r][i0]);
                accA[r] = fmaf(hv.x, wA[0], accA[r]); accA[r] = fmaf(hv.y, wA[1], accA[r]);
                accA[r] = fmaf(hv.z, wA[2], accA[r]); accA[r] = fmaf(hv.w, wA[3], accA[r]);
                accB[r] = fmaf(hv.x, wB[0], accB[r]); accB[r] = fmaf(hv.y, wB[1], accB[r]);
                accB[r] = fmaf(hv.z, wB[2], accB[r]); accB[r] = fmaf(hv.w, wB[3], accB[r]);
            }
        }
        // LayerNorm over H + relu (in-wave shuffle reduce: lane holds cols l, l+64)
        const float gA = g[cA], gB = g[cB], beA = be[cA], beB = be[cB];
        #pragma unroll
        for (int r = 0; r < 16; ++r) {
            const float a0 = accA[r], a1 = accB[r];
            float s1 = a0 + a1;
            float s2 = a0*a0 + a1*a1;
            #pragma unroll
            for (int off = 32; off > 0; off >>= 1) {
                s1 += __shfl_xor(s1, off, 64);
                s2 += __shfl_xor(s2, off, 64);
            }
            const float mu   = s1 * 0.0078125f;           // /128
            const float varr = fmaxf(s2 * 0.0078125f - mu*mu, 0.f);
            const float inv  = rsqrtf(varr + 1e-5f);
            const float vA = fmaf((a0 - mu) * inv, gA, beA);
            const float vB = fmaf((a1 - mu) * inv, gB, beB);
            hbuf[row0+r][cA] = fmaxf(vA, 0.f);
            hbuf[row0+r][cB] = fmaxf(vB, 0.f);
        }
        __syncthreads();
    };

    spectral(w0);
    conv(Ws1, bs1, Wn1, bn1, g1, be1);
    spectral(w2);
    conv(Ws3, bs3, Wn3, bn3, g3, be3);

    // ---------------- output projection: out = h @ Wo + bo ----------------
    {
        const int f  = lane & 7;
        const int r2 = lane >> 3;
        #pragma unroll
        for (int p = 0; p < 2; ++p) {
            const int n = wave * 8 + r2 + p * 32;
            float acc = bo[f];
            for (int ii = 0; ii < 32; ++ii) {
                const int i = 4 * ((ii + n) & 31);   // row-skewed start: avoids same-bank stride
                const float4 hv = *reinterpret_cast<const float4*>(&hbuf[n][i]);
                acc = fmaf(hv.x, Wo[(i+0)*FP + f], acc);
                acc = fmaf(hv.y, Wo[(i+1)*FP + f], acc);
                acc = fmaf(hv.z, Wo[(i+2)*FP + f], acc);
                acc = fmaf(hv.w, Wo[(i+3)*FP + f], acc);
            }
            out[(size_t)b * (NN*FP) + n*FP + f] = acc;
        }
    }
}

extern "C" void kernel_launch(void* const* d_in, const int* in_sizes, int n_in,
                              void* d_out, int out_size, void* d_ws, size_t ws_size,
                              hipStream_t stream) {
    const float* x   = (const float*)d_in[0];
    const float* adj = (const float*)d_in[1];
    const float* U   = (const float*)d_in[2];
    const float* Wp  = (const float*)d_in[3];
    const float* bp  = (const float*)d_in[4];
    const float* w0  = (const float*)d_in[5];
    const float* w2  = (const float*)d_in[6];
    const float* Ws1 = (const float*)d_in[7];
    const float* bs1 = (const float*)d_in[8];
    const float* Wn1 = (const float*)d_in[9];
    const float* bn1 = (const float*)d_in[10];
    const float* g1  = (const float*)d_in[11];
    const float* be1 = (const float*)d_in[12];
    const float* Ws3 = (const float*)d_in[13];
    const float* bs3 = (const float*)d_in[14];
    const float* Wn3 = (const float*)d_in[15];
    const float* bn3 = (const float*)d_in[16];
    const float* g3  = (const float*)d_in[17];
    const float* be3 = (const float*)d_in[18];
    const float* Wo  = (const float*)d_in[19];
    const float* bo  = (const float*)d_in[20];
    float* out = (float*)d_out;

    sgn_fused<<<NG, 256, 0, stream>>>(x, adj, U, Wp, bp, w0, w2,
                                      Ws1, bs1, Wn1, bn1, g1, be1,
                                      Ws3, bs3, Wn3, bn3, g3, be3,
                                      Wo, bo, out);
}

// Round 2
// 677.929 us; speedup vs baseline: 5.0147x; 5.0147x over previous
//
#include <hip/hip_runtime.h>

#define NG 16384
#define GPB 4            // graphs per block
#define NBLK (NG/GPB)

typedef __bf16 bf16x8 __attribute__((ext_vector_type(8)));
typedef float  f32x4  __attribute__((ext_vector_type(4)));

__device__ __forceinline__ int swz128(int row, int e){ return ((((e>>3) ^ (row&7)) & 15)<<3) | (e&7); }
__device__ __forceinline__ int swz32 (int row, int e){ return ((((e>>3) ^ (row&3)) & 3)<<3) | (e&7); }

// ---------------- prep kernels ----------------
// ws f32 region: [0:512) U8 (n*8+k), [512:1024) V=adj@U8, [1024:1032) c8=colsum(U8),
// [1088:1216) c1=bs1+bn1, [1216:1344) c3=bs3+bn3.  bf16 region at byte 8192:
// wTT0[k][j][i] (131072), wTT2 (+131072), WsT1[j][i] (+262144), WnT1(+278528), WsT3(+294912), WnT3(+311296)
__global__ void prep_small(const float* __restrict__ adj, const float* __restrict__ U,
                           const float* __restrict__ bs1, const float* __restrict__ bn1,
                           const float* __restrict__ bs3, const float* __restrict__ bn3,
                           float* __restrict__ ws){
    int t = threadIdx.x;
    if (t < 512){
        int n = t>>3, k = t&7;
        ws[t] = U[n*64+k];
        float v = 0.f;
        for (int m=0;m<64;++m) v += adj[n*64+m]*U[m*64+k];
        ws[512+t] = v;
    }
    if (t < 8){ float s=0.f; for(int n=0;n<64;++n) s += U[n*64+t]; ws[1024+t] = s; }
    if (t < 128){ ws[1088+t] = bs1[t]+bn1[t]; ws[1216+t] = bs3[t]+bn3[t]; }
}

__global__ void prep_w(const float* __restrict__ w0, const float* __restrict__ w2,
                       const float* __restrict__ Ws1, const float* __restrict__ Wn1,
                       const float* __restrict__ Ws3, const float* __restrict__ Wn3,
                       __bf16* __restrict__ wb){
    int id = blockIdx.x*256 + threadIdx.x;        // 327680 total
    if (id < 262144){
        const float* src = (id < 131072) ? w0 : w2;
        int r = id & 131071;
        int i = r>>10, j = (r>>3)&127, k = r&7;   // w[i][j][k] source-order coalesced
        __bf16* dst = wb + ((id<131072) ? 0 : 131072);
        dst[(k<<14) + (j<<7) + i] = (__bf16)src[r];
    } else {
        int r = id - 262144; int m = r>>14; int q = r&16383;
        int i = q>>7, j = q&127;
        const float* src = (m==0)?Ws1:(m==1)?Wn1:(m==2)?Ws3:Wn3;
        wb[262144 + (m<<14) + (j<<7) + i] = (__bf16)src[q];
    }
}

// ---------------- fused main kernel ----------------
__global__ __launch_bounds__(512, 2)
void sgn_main(const float* __restrict__ x,  const float* __restrict__ Wp, const float* __restrict__ bp,
              const float* __restrict__ g1, const float* __restrict__ be1,
              const float* __restrict__ g3, const float* __restrict__ be3,
              const float* __restrict__ Wo, const float* __restrict__ bo,
              const float* __restrict__ wsf, const __bf16* __restrict__ wsbf,
              float* __restrict__ out)
{
    __shared__ __align__(16) __bf16 h_s[GPB*64*128];     // 64 KB, swz128 by node row
    __shared__ __align__(16) __bf16 xfA_s[8*16*128];     // 32 KB, [mode][grow(16)][i], swz128 by grow
    __shared__ __align__(16) __bf16 of_s[32*128];        // 8 KB, rows s=g*8+k, swz128
    __shared__ __align__(16) __bf16 expB_s[GPB*128*32];  // 32 KB, [g][col][kdim], swz32 by col
    __shared__ __align__(16) __bf16 expA_s[64*32];       // 4 KB, [n][kdim], swz32 by n
    __shared__ __align__(16) __bf16 woT_s[16*128];       // 4 KB, [f][i], swz128 by f
    __shared__ float U8_s[512];
    __shared__ float cb_s[768];                           // c1,c3,g1,be1,g3,be3
    __shared__ float y_s[256];                            // y[g][k][f]
    __shared__ float c8_s[8];

    const int t   = threadIdx.x;
    const int w   = t>>6;
    const int l   = t&63;
    const int l15 = l&15;
    const int lg  = l>>4;
    const size_t xbase = (size_t)blockIdx.x * (GPB*512);
    const f32x4 zf4 = {0.f,0.f,0.f,0.f};

    // ---- P0a: stage x (reusing expB region), load U8/c8/cb, build expA & woT ----
    {
        float* xs = (float*)expB_s;
        ((float4*)xs)[t] = ((const float4*)(x + xbase))[t];   // 512*16B = 8KB
        U8_s[t] = wsf[t];
        if (t < 8) c8_s[t] = wsf[1024+t];
        for (int i=t;i<768;i+=512){
            int which = i>>7, c = i&127;
            float v = (which==0)?wsf[1088+c]:(which==1)?wsf[1216+c]:
                      (which==2)?g1[c]:(which==3)?be1[c]:(which==4)?g3[c]:be3[c];
            cb_s[i] = v;
        }
        for (int idx=t; idx<1024; idx+=512){ int j = idx>>7, i = idx&127;
            woT_s[j*128 + swz128(j,i)] = (__bf16)Wo[i*8+j]; }
        for (int idx=t; idx<2048; idx+=512){ int n = idx>>5, k = idx&31;
            float v = (k<8)? wsf[n*8+k] : (k<16? wsf[512+n*8+(k-8)] : 0.f);
            expA_s[n*32 + swz32(n,k)] = (__bf16)v; }
    }
    __syncthreads();

    // ---- P0b: y[g][k][f] = sum_n U8[n][k] * x[g][n][f] ----
    if (t < 256){
        int g = t>>6, k = (t>>3)&7, f = t&7;
        const float* xs = (const float*)expB_s;
        float s = 0.f;
        for (int n=0;n<64;++n) s += U8_s[n*8+k]*xs[g*512 + n*8 + f];
        y_s[(g*8+k)*8+f] = s;
    }
    __syncthreads();

    // ---- P0c: zero expB k=16..31 slots (stay zero both layers) ----
    for (int idx=t; idx<8192; idx+=512){
        int gI = idx>>11, col = (idx>>4)&127, k = 16+(idx&15);
        expB_s[(gI*128+col)*32 + swz32(col,k)] = (__bf16)0.f;
    }
    // ---- P0d: xf0[g][k][j] = sum_f y*Wp + c8[k]*bp[j] -> xfA ----
    {
        int g = t>>7, j = t&127;
        float a[8];
        #pragma unroll
        for (int k=0;k<8;++k) a[k] = c8_s[k]*bp[j];
        #pragma unroll
        for (int f=0;f<8;++f){
            float wp = Wp[f*128+j];
            #pragma unroll
            for (int k=0;k<8;++k) a[k] += y_s[(g*8+k)*8+f]*wp;
        }
        #pragma unroll
        for (int k=0;k<8;++k) xfA_s[(k*16+g)*128 + swz128(g,j)] = (__bf16)a[k];
    }
    __syncthreads();

    // ---- P1: of[g][k][:] = xf[g][k][:] @ w_k  (wave w = mode, M=graphs) ----
    auto P1 = [&](const __bf16* wtt){
        const __bf16* wttk = wtt + (w<<14);
        bf16x8 afr[4];
        #pragma unroll
        for (int ks=0;ks<4;++ks)
            afr[ks] = *(const bf16x8*)&xfA_s[(w*16+l15)*128 + swz128(l15, ks*32+lg*8)];
        f32x4 acc[8];
        #pragma unroll
        for (int jt=0;jt<8;++jt) acc[jt]=zf4;
        #pragma unroll
        for (int jt=0;jt<8;++jt){
            #pragma unroll
            for (int ks=0;ks<4;++ks){
                bf16x8 bfr = *(const bf16x8*)&wttk[(jt*16+l15)*128 + ks*32 + lg*8];
                acc[jt] = __builtin_amdgcn_mfma_f32_16x16x32_bf16(afr[ks], bfr, acc[jt], 0,0,0);
            }
        }
        if (l < 16){
            #pragma unroll
            for (int jt=0;jt<8;++jt){
                #pragma unroll
                for (int e=0;e<4;++e){
                    int row = e*8+w, c = jt*16+l15;
                    of_s[row*128 + swz128(row, c)] = (__bf16)acc[jt][e];
                }
            }
        }
    };

    // ---- P2: A=of@Ws, B=of@Wn (M=32 stacked), store transposed into expB ----
    auto P2 = [&](const __bf16* wsT, const __bf16* wnT){
        bf16x8 bS[4], bN[4];
        #pragma unroll
        for (int ks=0;ks<4;++ks){
            int idx = (w*16+l15)*128 + ks*32 + lg*8;
            bS[ks] = *(const bf16x8*)&wsT[idx];
            bN[ks] = *(const bf16x8*)&wnT[idx];
        }
        f32x4 aS[2], aN[2];
        aS[0]=zf4; aS[1]=zf4; aN[0]=zf4; aN[1]=zf4;
        #pragma unroll
        for (int mt=0;mt<2;++mt){
            #pragma unroll
            for (int ks=0;ks<4;++ks){
                int row = mt*16+l15;
                bf16x8 a = *(const bf16x8*)&of_s[row*128 + swz128(row, ks*32+lg*8)];
                aS[mt] = __builtin_amdgcn_mfma_f32_16x16x32_bf16(a, bS[ks], aS[mt], 0,0,0);
                aN[mt] = __builtin_amdgcn_mfma_f32_16x16x32_bf16(a, bN[ks], aN[mt], 0,0,0);
            }
        }
        #pragma unroll
        for (int mt=0;mt<2;++mt){
            int s0 = mt*16 + lg*4, gI = s0>>3, k0 = s0&7, col = w*16+l15;
            #pragma unroll
            for (int e=0;e<4;++e){
                expB_s[(gI*128+col)*32 + swz32(col, k0+e)]   = (__bf16)aS[mt][e];
                expB_s[(gI*128+col)*32 + swz32(col, 8+k0+e)] = (__bf16)aN[mt][e];
            }
        }
    };

    // ---- P3: o = [U8|V]@[A;B] + bias, LN, relu -> h_s ----
    auto P3 = [&](int cbi, int gi, int bei){
        int g = w>>1;
        #pragma unroll
        for (int mt2=0; mt2<2; ++mt2){
            int mtg = 2*(w&1) + mt2;
            int na  = mtg*16 + l15;
            bf16x8 a = *(const bf16x8*)&expA_s[na*32 + swz32(na, lg*8)];
            f32x4 acc[8];
            #pragma unroll
            for (int jt=0;jt<8;++jt){
                int col = jt*16 + l15;
                bf16x8 bfr = *(const bf16x8*)&expB_s[(g*128+col)*32 + swz32(col, lg*8)];
                acc[jt] = __builtin_amdgcn_mfma_f32_16x16x32_bf16(a, bfr, zf4, 0,0,0);
            }
            #pragma unroll
            for (int e=0;e<4;++e){
                int n = mtg*16 + lg*4 + e;
                float o[8]; float s1=0.f, s2=0.f;
                #pragma unroll
                for (int jt=0;jt<8;++jt){
                    int c = jt*16+l15;
                    o[jt] = acc[jt][e] + cb_s[cbi*128+c];
                    s1 += o[jt]; s2 += o[jt]*o[jt];
                }
                #pragma unroll
                for (int m=1;m<16;m<<=1){ s1 += __shfl_xor(s1, m, 64); s2 += __shfl_xor(s2, m, 64); }
                float mu  = s1*(1.f/128.f);
                float varr= fmaxf(s2*(1.f/128.f)-mu*mu, 0.f);
                float inv = rsqrtf(varr + 1e-5f);
                #pragma unroll
                for (int jt=0;jt<8;++jt){
                    int c = jt*16+l15;
                    float hv = fmaxf((o[jt]-mu)*inv*cb_s[gi*128+c] + cb_s[bei*128+c], 0.f);
                    h_s[(g*64+n)*128 + swz128(n, c)] = (__bf16)hv;
                }
            }
        }
    };

    const __bf16* wtt0  = wsbf;
    const __bf16* wtt2  = wsbf + 131072;
    const __bf16* WsT1b = wsbf + 262144;
    const __bf16* WnT1b = wsbf + 278528;
    const __bf16* WsT3b = wsbf + 294912;
    const __bf16* WnT3b = wsbf + 311296;

    P1(wtt0);            __syncthreads();
    P2(WsT1b, WnT1b);    __syncthreads();
    P3(0, 2, 3);         __syncthreads();

    // ---- P4: xf2[g][k][j] = sum_n U8[n][k] * h1[g][n][j] ----
    {
        int g = t>>7, j = t&127;
        float a[8] = {0.f,0.f,0.f,0.f,0.f,0.f,0.f,0.f};
        for (int n=0;n<64;++n){
            float hv = (float)h_s[(g*64+n)*128 + swz128(n,j)];
            #pragma unroll
            for (int k=0;k<8;++k) a[k] += U8_s[n*8+k]*hv;
        }
        #pragma unroll
        for (int k=0;k<8;++k) xfA_s[(k*16+g)*128 + swz128(g,j)] = (__bf16)a[k];
    }
    __syncthreads();

    P1(wtt2);            __syncthreads();
    P2(WsT3b, WnT3b);    __syncthreads();
    P3(1, 4, 5);         __syncthreads();

    // ---- P5: out = h3 @ Wo + bo  (M=256 stacked, N=8 in 16-tile) ----
    #pragma unroll
    for (int mt2=0; mt2<2; ++mt2){
        int mt = 2*w + mt2;
        f32x4 acc = zf4;
        int m = mt*16 + l15, gg = m>>6, n = m&63;
        #pragma unroll
        for (int ks=0;ks<4;++ks){
            bf16x8 a   = *(const bf16x8*)&h_s[(gg*64+n)*128 + swz128(n, ks*32+lg*8)];
            bf16x8 bfr = *(const bf16x8*)&woT_s[l15*128 + swz128(l15, ks*32+lg*8)];
            acc = __builtin_amdgcn_mfma_f32_16x16x32_bf16(a, bfr, acc, 0,0,0);
        }
        if (l15 < 8){
            float bov = bo[l15];
            #pragma unroll
            for (int e=0;e<4;++e){
                int mm = mt*16 + lg*4 + e, gw = mm>>6, nw = mm&63;
                out[((size_t)(blockIdx.x*GPB+gw))*512 + nw*8 + l15] = acc[e] + bov;
            }
        }
    }
}

extern "C" void kernel_launch(void* const* d_in, const int* in_sizes, int n_in,
                              void* d_out, int out_size, void* d_ws, size_t ws_size,
                              hipStream_t stream) {
    const float* x   = (const float*)d_in[0];
    const float* adj = (const float*)d_in[1];
    const float* U   = (const float*)d_in[2];
    const float* Wp  = (const float*)d_in[3];
    const float* bp  = (const float*)d_in[4];
    const float* w0  = (const float*)d_in[5];
    const float* w2  = (const float*)d_in[6];
    const float* Ws1 = (const float*)d_in[7];
    const float* bs1 = (const float*)d_in[8];
    const float* Wn1 = (const float*)d_in[9];
    const float* bn1 = (const float*)d_in[10];
    const float* g1  = (const float*)d_in[11];
    const float* be1 = (const float*)d_in[12];
    const float* Ws3 = (const float*)d_in[13];
    const float* bs3 = (const float*)d_in[14];
    const float* Wn3 = (const float*)d_in[15];
    const float* bn3 = (const float*)d_in[16];
    const float* g3  = (const float*)d_in[17];
    const float* be3 = (const float*)d_in[18];
    const float* Wo  = (const float*)d_in[19];
    const float* bo  = (const float*)d_in[20];
    float* out = (float*)d_out;

    float*  wsf  = (float*)d_ws;
    __bf16* wsbf = (__bf16*)((char*)d_ws + 8192);

    prep_small<<<1, 512, 0, stream>>>(adj, U, bs1, bn1, bs3, bn3, wsf);
    prep_w<<<1280, 256, 0, stream>>>(w0, w2, Ws1, Wn1, Ws3, Wn3, wsbf);
    sgn_main<<<NBLK, 512, 0, stream>>>(x, Wp, bp, g1, be1, g3, be3, Wo, bo,
                                       wsf, (const __bf16*)wsbf, out);
}

// Round 4
// 428.254 us; speedup vs baseline: 7.9383x; 1.5830x over previous
//
#include <hip/hip_runtime.h>

#define NG 16384

typedef __bf16 bf16x8 __attribute__((ext_vector_type(8)));
typedef float  f32x4  __attribute__((ext_vector_type(4)));

#define MFMA(a,b,c) __builtin_amdgcn_mfma_f32_16x16x32_bf16(a,b,c,0,0,0)
#define LGKM_FENCE() do { asm volatile("s_waitcnt lgkmcnt(0)" ::: "memory"); \
                          __builtin_amdgcn_sched_barrier(0); } while(0)

// ---- workspace byte offsets ----
#define OFF_U8T   0          // bf16 [8][64]    U8T[k][n]
#define OFF_EA    1024       // bf16 [64][16]   [n][slot] slot<8:U8, 8..15:V
#define OFF_WOT   3072       // bf16 [8][128]   [f][i] = Wo[i][f]
#define OFF_C1    5120       // f32 [128] bs1+bn1
#define OFF_C3    5632       // f32 [128] bs3+bn3
#define OFF_C8    6144       // f32 [8] colsum(U8)
#define OFF_PST   8192       // bf16 [8][128][8]  Ps[k][j][f]
#define OFF_PNT   24576      // bf16 [8][128][8]
#define OFF_ES    40960      // bf16 [8][128]
#define OFF_EN    43008      // bf16 [8][128]
#define OFF_QST   49152      // bf16 [8][128][128] Qs[k][j'][i]
#define OFF_QNT   311296     // bf16 [8][128][128]
#define OFF_XF2   1048576ULL // bf16 [8][16384][128]  xf2[k][g][j]
#define OFF_AB    35651584ULL// K_A: ABs[g][j][8] (33.55MB) then ABn; K_B2 reuses as P3[16][g][j]
#define ABPLANE   16777216ULL   // elems per AB plane
#define P3PLANE   2097152ULL    // elems per P3 slot plane

// =================== prep: fold all weights ===================
__global__ void prep_all(const float* __restrict__ adj, const float* __restrict__ U,
                         const float* __restrict__ Wp,  const float* __restrict__ bp,
                         const float* __restrict__ w0,  const float* __restrict__ w2,
                         const float* __restrict__ Ws1, const float* __restrict__ bs1,
                         const float* __restrict__ Wn1, const float* __restrict__ bn1,
                         const float* __restrict__ Ws3, const float* __restrict__ Wn3,
                         const float* __restrict__ bs3, const float* __restrict__ bn3,
                         const float* __restrict__ Wo,  char* __restrict__ ws)
{
    const int bid = blockIdx.x, t = threadIdx.x;
    __bf16* U8T = (__bf16*)(ws + OFF_U8T);
    __bf16* EA  = (__bf16*)(ws + OFF_EA);
    __bf16* WOT = (__bf16*)(ws + OFF_WOT);
    float*  C1  = (float*)(ws + OFF_C1);
    float*  C3  = (float*)(ws + OFF_C3);
    float*  C8  = (float*)(ws + OFF_C8);
    __bf16* PST = (__bf16*)(ws + OFF_PST);
    __bf16* PNT = (__bf16*)(ws + OFF_PNT);
    __bf16* ES  = (__bf16*)(ws + OFF_ES);
    __bf16* EN  = (__bf16*)(ws + OFF_EN);
    __bf16* QST = (__bf16*)(ws + OFF_QST);
    __bf16* QNT = (__bf16*)(ws + OFF_QNT);
    __shared__ float sm[2176];

    if (bid == 0) {
        for (int p = t; p < 512; p += 256) {
            int n = p >> 3, k = p & 7;
            float u = U[n*64 + k];
            U8T[k*64 + n] = (__bf16)u;
            EA[n*16 + k]  = (__bf16)u;
            float v = 0.f;
            for (int m = 0; m < 64; ++m) v += adj[n*64 + m] * U[m*64 + k];
            EA[n*16 + 8 + k] = (__bf16)v;
        }
        if (t < 8) { float s = 0.f; for (int n = 0; n < 64; ++n) s += U[n*64 + t]; C8[t] = s; }
        if (t < 128) { C1[t] = bs1[t] + bn1[t]; C3[t] = bs3[t] + bn3[t]; }
        for (int p = t; p < 1024; p += 256) { int f = p >> 7, i = p & 127; WOT[f*128 + i] = (__bf16)Wo[i*8 + f]; }
    } else if (bid <= 16) {
        const int id = bid - 1, k = id & 7, mat = id >> 3;
        const float* W = mat ? Wn1 : Ws1;
        float* Wp0 = sm;            // [8][128]
        float* d0  = sm + 1024;     // [128]
        if (t < 128) {
            float a[8] = {0,0,0,0,0,0,0,0};
            for (int j = 0; j < 128; ++j) {
                float wv = w0[(j*128 + t)*8 + k];
                #pragma unroll
                for (int f = 0; f < 8; ++f) a[f] += Wp[f*128 + j] * wv;
            }
            #pragma unroll
            for (int f = 0; f < 8; ++f) Wp0[f*128 + t] = a[f];
        } else {
            int j2 = t - 128; float d = 0.f;
            for (int j = 0; j < 128; ++j) d += bp[j] * w0[(j*128 + j2)*8 + k];
            d0[j2] = d;
        }
        __syncthreads();
        if (t < 128) {
            float a[8] = {0,0,0,0,0,0,0,0};
            for (int j2 = 0; j2 < 128; ++j2) {
                float wv = W[j2*128 + t];
                #pragma unroll
                for (int f = 0; f < 8; ++f) a[f] += Wp0[f*128 + j2] * wv;
            }
            __bf16* dst = (mat ? PNT : PST) + (k*128 + t)*8;
            #pragma unroll
            for (int f = 0; f < 8; ++f) dst[f] = (__bf16)a[f];
        } else {
            int jp = t - 128; float e = 0.f;
            for (int j2 = 0; j2 < 128; ++j2) e += d0[j2] * W[j2*128 + jp];
            (mat ? EN : ES)[k*128 + jp] = (__bf16)e;
        }
    } else {
        const int id = bid - 17, slot = id & 15, jc = id >> 4;   // jc 0..15 (8-wide j' chunks)
        const int k = slot & 7, mat = slot >> 3;
        const float* W3 = mat ? Wn3 : Ws3;
        __bf16* dst = (mat ? QNT : QST) + k*16384;
        float* W3s = sm;  // [128][8]
        for (int p = t; p < 1024; p += 256) { int m = p >> 3, jj = p & 7; W3s[m*8 + jj] = W3[m*128 + jc*8 + jj]; }
        __syncthreads();
        const int isub = t >> 3, jj = t & 7;
        for (int ic = 0; ic < 4; ++ic) {
            int i = ic*32 + isub;
            float a = 0.f;
            for (int m = 0; m < 128; ++m) a += w2[(i*128 + m)*8 + k] * W3s[m*8 + jj];
            dst[(jc*8 + jj)*128 + i] = (__bf16)a;
        }
    }
}

// =================== K_A: x -> y -> A1,B1 (VALU, K=8 folded) ===================
__global__ __launch_bounds__(256, 2)
void k_a(const float* __restrict__ x, char* __restrict__ ws)
{
    __shared__ float  x_s[16*512];
    __shared__ __bf16 ps_s[8192], pn_s[8192];
    __shared__ __bf16 es_s[1024], en_s[1024];
    __shared__ __bf16 u8t_s[512];
    __shared__ float  y_s[16*64];
    __shared__ float  c8_s[8];

    const int t = threadIdx.x;
    const size_t g0 = (size_t)blockIdx.x * 16;
    const __bf16* PST = (const __bf16*)(ws + OFF_PST);
    const __bf16* PNT = (const __bf16*)(ws + OFF_PNT);
    const __bf16* ESg = (const __bf16*)(ws + OFF_ES);
    const __bf16* ENg = (const __bf16*)(ws + OFF_EN);
    const __bf16* U8T = (const __bf16*)(ws + OFF_U8T);
    const float*  C8  = (const float*)(ws + OFF_C8);
    __bf16* ABs = (__bf16*)(ws + OFF_AB);
    __bf16* ABn = ABs + ABPLANE;

    #pragma unroll
    for (int c = 0; c < 8; ++c)
        ((float4*)x_s)[t + 256*c] = ((const float4*)(x + g0*512))[t + 256*c];
    #pragma unroll
    for (int c = 0; c < 4; ++c) {
        ((bf16x8*)ps_s)[t + 256*c] = ((const bf16x8*)PST)[t + 256*c];
        ((bf16x8*)pn_s)[t + 256*c] = ((const bf16x8*)PNT)[t + 256*c];
    }
    if (t < 128) { ((bf16x8*)es_s)[t] = ((const bf16x8*)ESg)[t]; ((bf16x8*)en_s)[t] = ((const bf16x8*)ENg)[t]; }
    if (t < 64)  ((bf16x8*)u8t_s)[t] = ((const bf16x8*)U8T)[t];
    if (t < 8)   c8_s[t] = C8[t];
    __syncthreads();

    { // y[g][k][f] = sum_n U8[n][k]*x[g][n][f]
        const int g = t >> 4, k = (t >> 1) & 7, fh = (t & 1) * 4;
        float a0 = 0, a1 = 0, a2 = 0, a3 = 0;
        for (int nn = 0; nn < 64; ++nn) {
            int n = (nn + g) & 63;
            float u = (float)u8t_s[k*64 + n];
            float4 xv = *(const float4*)&x_s[g*512 + n*8 + fh];
            a0 += u*xv.x; a1 += u*xv.y; a2 += u*xv.z; a3 += u*xv.w;
        }
        y_s[(g*8 + k)*8 + fh + 0] = a0; y_s[(g*8 + k)*8 + fh + 1] = a1;
        y_s[(g*8 + k)*8 + fh + 2] = a2; y_s[(g*8 + k)*8 + fh + 3] = a3;
    }
    __syncthreads();

    #pragma unroll
    for (int c = 0; c < 8; ++c) {
        const int p = t + 256*c, g = p >> 7, j = p & 127;
        const float* yg = &y_s[g*64];
        bf16x8 oA, oB;
        #pragma unroll
        for (int k = 0; k < 8; ++k) {
            float fa = c8_s[k] * (float)es_s[k*128 + j];
            float fb = c8_s[k] * (float)en_s[k*128 + j];
            bf16x8 pv = *(const bf16x8*)&ps_s[(k*128 + j)*8];
            bf16x8 qv = *(const bf16x8*)&pn_s[(k*128 + j)*8];
            #pragma unroll
            for (int f = 0; f < 8; ++f) {
                float yv = yg[k*8 + f];
                fa += yv * (float)pv[f];
                fb += yv * (float)qv[f];
            }
            oA[k] = (__bf16)fa; oB[k] = (__bf16)fb;
        }
        *(bf16x8*)&ABs[((g0 + g)*128 + j)*8] = oA;
        *(bf16x8*)&ABn[((g0 + g)*128 + j)*8] = oB;
    }
}

// =================== K_B1: expand+LN+relu -> contract (wave-per-graph) ===================
__global__ __launch_bounds__(256, 3)
void k_b1(char* __restrict__ ws, const float* __restrict__ g1, const float* __restrict__ be1)
{
    __shared__ __bf16 hws[4][128*40];   // per-wave [j][n32 pad40]
    __shared__ __bf16 u8t_s[8*72];
    __shared__ __bf16 ea_s[64*24];
    __shared__ float  cb[384];          // c1 | g1 | be1

    const int t = threadIdx.x;
    const __bf16* U8T = (const __bf16*)(ws + OFF_U8T);
    const __bf16* EA  = (const __bf16*)(ws + OFF_EA);
    const float*  C1  = (const float*)(ws + OFF_C1);
    const __bf16* ABs = (const __bf16*)(ws + OFF_AB);
    __bf16* XF2 = (__bf16*)(ws + OFF_XF2);

    for (int p = t; p < 512;  p += 256) { int k = p >> 6, n = p & 63; u8t_s[k*72 + n] = U8T[p]; }
    for (int p = t; p < 1024; p += 256) { int n = p >> 4, s = p & 15; ea_s[n*24 + s] = EA[p]; }
    for (int p = t; p < 384;  p += 256) {
        int wh = p >> 7, c = p & 127;
        cb[p] = (wh == 0) ? C1[c] : (wh == 1) ? g1[c] : be1[c];
    }
    __syncthreads();

    const int w = t >> 6, l = t & 63, l15 = l & 15, lg = l >> 4;
    __bf16* hw = &hws[w][0];
    const bf16x8 z = {};
    const f32x4  zf = {0.f, 0.f, 0.f, 0.f};

    for (int gi = 0; gi < 4; ++gi) {
        const size_t g = ((size_t)blockIdx.x*4 + w)*4 + gi;
        bf16x8 Bf[8];
        #pragma unroll
        for (int jt = 0; jt < 8; ++jt)
            Bf[jt] = (lg < 2) ? *(const bf16x8*)&ABs[lg*ABPLANE + (g*128 + l15 + 16*jt)*8] : z;

        f32x4 xacc[8];
        #pragma unroll
        for (int jt = 0; jt < 8; ++jt) xacc[jt] = zf;

        #pragma unroll
        for (int mt2 = 0; mt2 < 2; ++mt2) {
            LGKM_FENCE();  // WAR: hw reuse
            #pragma unroll
            for (int sub = 0; sub < 2; ++sub) {
                const int mt = mt2*2 + sub;
                bf16x8 Af = (lg < 2) ? *(const bf16x8*)&ea_s[(mt*16 + l15)*24 + lg*8] : z;
                f32x4 D[8];
                #pragma unroll
                for (int jt = 0; jt < 8; ++jt) D[jt] = MFMA(Af, Bf[jt], zf);
                #pragma unroll
                for (int e = 0; e < 4; ++e) {
                    float o[8], s1 = 0.f, s2 = 0.f;
                    #pragma unroll
                    for (int jt = 0; jt < 8; ++jt) {
                        o[jt] = D[jt][e] + cb[l15 + 16*jt];
                        s1 += o[jt]; s2 += o[jt]*o[jt];
                    }
                    #pragma unroll
                    for (int m = 1; m < 16; m <<= 1) { s1 += __shfl_xor(s1, m, 64); s2 += __shfl_xor(s2, m, 64); }
                    const float mu  = s1 * 0.0078125f;
                    const float var = fmaxf(s2 * 0.0078125f - mu*mu, 0.f);
                    const float inv = rsqrtf(var + 1e-5f);
                    const int nrow = sub*16 + lg*4 + e;
                    #pragma unroll
                    for (int jt = 0; jt < 8; ++jt) {
                        const int j = l15 + 16*jt;
                        float hv = fmaxf((o[jt] - mu)*inv*cb[128 + j] + cb[256 + j], 0.f);
                        hw[j*40 + nrow] = (__bf16)hv;
                    }
                }
            }
            LGKM_FENCE();  // writes visible to in-wave reads
            bf16x8 Au = (l15 < 8) ? *(const bf16x8*)&u8t_s[l15*72 + mt2*32 + lg*8] : z;
            #pragma unroll
            for (int jt = 0; jt < 8; ++jt) {
                bf16x8 Bh = *(const bf16x8*)&hw[(l15 + 16*jt)*40 + lg*8];
                xacc[jt] = MFMA(Au, Bh, xacc[jt]);
            }
        }
        if (l < 32) {
            #pragma unroll
            for (int jt = 0; jt < 8; ++jt)
                #pragma unroll
                for (int e = 0; e < 4; ++e) {
                    const int k = lg*4 + e;
                    XF2[((size_t)k*NG + g)*128 + l15 + 16*jt] = (__bf16)xacc[jt][e];
                }
        }
    }
}

// =================== K_B2: A3/B3 = xf2 @ Qfold (big-M GEMM) ===================
__global__ __launch_bounds__(256, 4)
void k_b2(char* __restrict__ ws)
{
    __shared__ __bf16 q_s[16384];  // [j'][i] chunk-XOR swizzled

    const int bid = blockIdx.x, t = threadIdx.x;
    const int slot = bid & 15, gc = bid >> 4;
    const int k = slot & 7;
    const __bf16* QT  = (const __bf16*)(ws + (slot < 8 ? OFF_QST : OFF_QNT)) + k*16384;
    const __bf16* XF2 = (const __bf16*)(ws + OFF_XF2);
    __bf16* P3 = (__bf16*)(ws + OFF_AB) + (size_t)slot * P3PLANE;

    #pragma unroll
    for (int c = 0; c < 8; ++c) {
        const int id = t + 256*c, j = id >> 4, ic = id & 15;
        *(bf16x8*)&q_s[j*128 + ((ic ^ (j & 7))*8)] = *(const bf16x8*)&QT[j*128 + ic*8];
    }
    __syncthreads();

    const int w = t >> 6, l = t & 63, l15 = l & 15, lg = l >> 4;
    const f32x4 zf = {0.f, 0.f, 0.f, 0.f};

    #pragma unroll
    for (int mi = 0; mi < 2; ++mi) {
        const int mt = w*2 + mi;
        const int grow = gc*128 + mt*16;
        bf16x8 Af[4];
        #pragma unroll
        for (int ks = 0; ks < 4; ++ks)
            Af[ks] = *(const bf16x8*)&XF2[((size_t)k*NG + grow + l15)*128 + ks*32 + lg*8];
        #pragma unroll
        for (int jt = 0; jt < 8; ++jt) {
            const int j = l15 + 16*jt;
            f32x4 acc = zf;
            #pragma unroll
            for (int ks = 0; ks < 4; ++ks) {
                bf16x8 Bq = *(const bf16x8*)&q_s[j*128 + (((ks*4 + lg) ^ (j & 7))*8)];
                acc = MFMA(Af[ks], Bq, acc);
            }
            #pragma unroll
            for (int e = 0; e < 4; ++e)
                P3[(size_t)(grow + lg*4 + e)*128 + j] = (__bf16)acc[e];
        }
    }
}

// =================== K_B3: expand+LN+relu -> out projection ===================
__global__ __launch_bounds__(256, 3)
void k_b3(char* __restrict__ ws, const float* __restrict__ g3, const float* __restrict__ be3,
          const float* __restrict__ bo, float* __restrict__ out)
{
    __shared__ __bf16 abw_s[4][128*16];  // per-wave [j][slot16] (chunk-swz)
    __shared__ __bf16 h3w_s[4][16*136];  // per-wave [n16][j pad136] (chunk-swz by n)
    __shared__ __bf16 wot_s[8*128];
    __shared__ __bf16 ea_s[64*24];
    __shared__ float  cb[384];
    __shared__ float  bo_s[8];

    const int t = threadIdx.x;
    const __bf16* WOT = (const __bf16*)(ws + OFF_WOT);
    const __bf16* EA  = (const __bf16*)(ws + OFF_EA);
    const float*  C3  = (const float*)(ws + OFF_C3);
    const __bf16* P3  = (const __bf16*)(ws + OFF_AB);

    if (t < 128) {
        const int f = t >> 4, ic = t & 15;
        *(bf16x8*)&wot_s[f*128 + ((ic ^ f)*8)] = *(const bf16x8*)&WOT[f*128 + ic*8];
    }
    for (int p = t; p < 1024; p += 256) { int n = p >> 4, s = p & 15; ea_s[n*24 + s] = EA[p]; }
    for (int p = t; p < 384;  p += 256) {
        int wh = p >> 7, c = p & 127;
        cb[p] = (wh == 0) ? C3[c] : (wh == 1) ? g3[c] : be3[c];
    }
    if (t < 8) bo_s[t] = bo[t];
    __syncthreads();

    const int w = t >> 6, l = t & 63, l15 = l & 15, lg = l >> 4;
    __bf16* abw = &abw_s[w][0];
    __bf16* h3w = &h3w_s[w][0];
    const bf16x8 z = {};
    const f32x4  zf = {0.f, 0.f, 0.f, 0.f};

    for (int gi = 0; gi < 4; ++gi) {
        const size_t g = ((size_t)blockIdx.x*4 + w)*4 + gi;
        LGKM_FENCE();  // WAR: abw reuse
        { // transpose-stage AB3 for this graph
            const int s = l & 15;
            #pragma unroll
            for (int c = 0; c < 4; ++c) {
                const int jc = (l >> 4) + 4*c;
                bf16x8 v = *(const bf16x8*)&P3[(size_t)s*P3PLANE + g*128 + jc*8];
                #pragma unroll
                for (int w8 = 0; w8 < 8; ++w8) {
                    const int j = jc*8 + w8;
                    abw[j*16 + (((s >> 3) ^ (j & 1))*8) + (s & 7)] = v[w8];
                }
            }
        }
        LGKM_FENCE();
        bf16x8 Bf[8];
        #pragma unroll
        for (int jt = 0; jt < 8; ++jt) {
            const int j = l15 + 16*jt;
            Bf[jt] = (lg < 2) ? *(const bf16x8*)&abw[j*16 + ((lg ^ (j & 1))*8)] : z;
        }
        #pragma unroll
        for (int mt = 0; mt < 4; ++mt) {
            bf16x8 Af = (lg < 2) ? *(const bf16x8*)&ea_s[(mt*16 + l15)*24 + lg*8] : z;
            f32x4 D[8];
            #pragma unroll
            for (int jt = 0; jt < 8; ++jt) D[jt] = MFMA(Af, Bf[jt], zf);
            LGKM_FENCE();  // WAR: h3w reuse from previous mt
            #pragma unroll
            for (int e = 0; e < 4; ++e) {
                float o[8], s1 = 0.f, s2 = 0.f;
                #pragma unroll
                for (int jt = 0; jt < 8; ++jt) {
                    o[jt] = D[jt][e] + cb[l15 + 16*jt];
                    s1 += o[jt]; s2 += o[jt]*o[jt];
                }
                #pragma unroll
                for (int m = 1; m < 16; m <<= 1) { s1 += __shfl_xor(s1, m, 64); s2 += __shfl_xor(s2, m, 64); }
                const float mu  = s1 * 0.0078125f;
                const float var = fmaxf(s2 * 0.0078125f - mu*mu, 0.f);
                const float inv = rsqrtf(var + 1e-5f);
                const int n16 = lg*4 + e;
                #pragma unroll
                for (int jt = 0; jt < 8; ++jt) {
                    const int j = l15 + 16*jt, jc2 = j >> 3;
                    float hv = fmaxf((o[jt] - mu)*inv*cb[128 + j] + cb[256 + j], 0.f);
                    h3w[n16*136 + ((jc2 ^ (n16 & 7))*8) + (j & 7)] = (__bf16)hv;
                }
            }
            LGKM_FENCE();
            f32x4 oacc = zf;
            #pragma unroll
            for (int ks = 0; ks < 4; ++ks) {
                bf16x8 Ah = *(const bf16x8*)&h3w[l15*136 + (((lg + 4*ks) ^ (l15 & 7))*8)];
                bf16x8 Bw = (l15 < 8) ? *(const bf16x8*)&wot_s[l15*128 + (((lg + 4*ks) ^ l15)*8)] : z;
                oacc = MFMA(Ah, Bw, oacc);
            }
            if (l15 < 8) {
                #pragma unroll
                for (int e = 0; e < 4; ++e) {
                    const int n = mt*16 + lg*4 + e;
                    out[g*512 + n*8 + l15] = oacc[e] + bo_s[l15];
                }
            }
        }
    }
}

extern "C" void kernel_launch(void* const* d_in, const int* in_sizes, int n_in,
                              void* d_out, int out_size, void* d_ws, size_t ws_size,
                              hipStream_t stream) {
    const float* x   = (const float*)d_in[0];
    const float* adj = (const float*)d_in[1];
    const float* U   = (const float*)d_in[2];
    const float* Wp  = (const float*)d_in[3];
    const float* bp  = (const float*)d_in[4];
    const float* w0  = (const float*)d_in[5];
    const float* w2  = (const float*)d_in[6];
    const float* Ws1 = (const float*)d_in[7];
    const float* bs1 = (const float*)d_in[8];
    const float* Wn1 = (const float*)d_in[9];
    const float* bn1 = (const float*)d_in[10];
    const float* g1  = (const float*)d_in[11];
    const float* be1 = (const float*)d_in[12];
    const float* Ws3 = (const float*)d_in[13];
    const float* bs3 = (const float*)d_in[14];
    const float* Wn3 = (const float*)d_in[15];
    const float* bn3 = (const float*)d_in[16];
    const float* g3  = (const float*)d_in[17];
    const float* be3 = (const float*)d_in[18];
    const float* Wo  = (const float*)d_in[19];
    const float* bo  = (const float*)d_in[20];
    float* out = (float*)d_out;
    char* ws = (char*)d_ws;

    prep_all<<<273, 256, 0, stream>>>(adj, U, Wp, bp, w0, w2, Ws1, bs1, Wn1, bn1,
                                      Ws3, Wn3, bs3, bn3, Wo, ws);
    k_a <<<NG/16, 256, 0, stream>>>(x, ws);
    k_b1<<<NG/16, 256, 0, stream>>>(ws, g1, be1);
    k_b2<<<(NG/128)*16, 256, 0, stream>>>(ws);
    k_b3<<<NG/16, 256, 0, stream>>>(ws, g3, be3, bo, out);
}